// Round 5
// baseline (125.358 us; speedup 1.0000x reference)
//
#include <hip/hip_runtime.h>

// DTW via min-plus scan for MI355X (gfx950). Round 19 = CALIBRATION PROBE.
// Kernel body is r18 unchanged (fastest family, 78.6us). kernel_launch
// enqueues THREE identical launches: serialized on-stream, idempotent
// outputs, graph-capture safe. dur_us ~= floor + 3K (baseline had 1K),
// so K = (dur - 78.6)/2. Resolves the kernel-vs-harness split that four
// flat rounds (issue -30%/-13%, chain -33%, +2-wave +3.2us) cannot:
//   A: K~36-38 (component-sum)  -> dur 150-155 -> TLP redesign next
//   B: K~23-25 (r13 probe)      -> dur 124-129 -> latency-chain attack
//   C: K<=10  (issue model)     -> dur <=99    -> harness floor, roofline

#define BIGF 1e30f
#define LL   1024
#define LOUT 32

using v4f = __attribute__((ext_vector_type(4))) float;

template<int CTRL>
__device__ __forceinline__ float dpp_self(float v) {   // invalid lanes keep own
    return __int_as_float(__builtin_amdgcn_update_dpp(
        __float_as_int(v), __float_as_int(v), CTRL, 0xF, 0xF, false));
}
template<int CTRL>
__device__ __forceinline__ float dpp_zero(float v) {   // invalid lanes get 0
    return __int_as_float(__builtin_amdgcn_update_dpp(
        0, __float_as_int(v), CTRL, 0xF, 0xF, false));
}
template<int CTRL, int RM>
__device__ __forceinline__ float dpp_self_rm(float v) { // masked rows keep own
    return __int_as_float(__builtin_amdgcn_update_dpp(
        __float_as_int(v), __float_as_int(v), CTRL, RM, 0xF, false));
}
template<int CTRL, int RM>
__device__ __forceinline__ float dpp_zero_rm(float v) { // masked rows get 0
    return __int_as_float(__builtin_amdgcn_update_dpp(
        0, __float_as_int(v), CTRL, RM, 0xF, false));
}
// validated r2-r18: whole-wave shift right 1 lane; lane 0 <- 0
__device__ __forceinline__ float wshr1z(float v) {
    return __int_as_float(__builtin_amdgcn_update_dpp(
        0, __float_as_int(v), 0x138 /*wave_shr:1*/, 0xF, 0xF, false));
}
__device__ __forceinline__ float rdlane(float v, int l) {
    return __int_as_float(__builtin_amdgcn_readlane(__float_as_int(v), l));
}

// inclusive wave64 min-scan, 6-op GCN form (validated r17)
__device__ __forceinline__ float scan_min64(float t) {
    t = fminf(t, dpp_self<0x111>(t));            // row_shr:1
    t = fminf(t, dpp_self<0x112>(t));            // row_shr:2
    t = fminf(t, dpp_self<0x114>(t));            // row_shr:4
    t = fminf(t, dpp_self<0x118>(t));            // row_shr:8
    t = fminf(t, dpp_self_rm<0x142, 0xA>(t));    // row_bcast:15, rows 1,3
    t = fminf(t, dpp_self_rm<0x143, 0xC>(t));    // row_bcast:31, rows 2,3
    return t;
}
// inclusive wave64 add-scan (validated r17)
__device__ __forceinline__ float scan_add64(float t) {
    t += dpp_zero<0x111>(t);
    t += dpp_zero<0x112>(t);
    t += dpp_zero<0x114>(t);
    t += dpp_zero<0x118>(t);
    t += dpp_zero_rm<0x142, 0xA>(t);
    t += dpp_zero_rm<0x143, 0xC>(t);
    return t;
}

__global__ __launch_bounds__(64)
__attribute__((amdgpu_waves_per_eu(1, 1)))   // 1 wave/EU: full register file
void dtw_kernel(const float* __restrict__ x, const float* __restrict__ patts,
                float* __restrict__ out) {
    const int lane = threadIdx.x;          // lane owns cols [16*lane, 16*lane+16)
    const bool l0  = (lane == 0);
    const int blk  = blockIdx.x;           // 0..1023 = (b,n)
    const int b    = blk >> 5, n = blk & 31;
    const float* __restrict__ xb = x + b * (12 * LL);
    const float* __restrict__ pn = patts + n * (12 * 32);

    // ---- pattern params into registers: lane r (r&31) holds row r ----
    float prm[12], p2r;
    {
        const int r = lane & 31;
        float s2 = 0.f;
#pragma unroll
        for (int d = 0; d < 12; ++d) {
            float v = pn[d * 32 + r];
            s2 = fmaf(v, v, s2);
            prm[d] = -2.0f * v;
        }
        p2r = s2;
    }

    // ---- x slice -> scalar regs (coalesced 16B/lane loads) ----
    float SX[12][16];
#pragma unroll
    for (int d = 0; d < 12; ++d) {
#pragma unroll
        for (int c = 0; c < 4; ++c) {
            v4f v = *(const v4f*)(xb + d * LL + 16 * lane + 4 * c);
            SX[d][4 * c + 0] = v.x;
            SX[d][4 * c + 1] = v.y;
            SX[d][4 * c + 2] = v.z;
            SX[d][4 * c + 3] = v.w;
        }
    }
    // x^2 from raw values
    float SX2[16];
#pragma unroll
    for (int k = 0; k < 16; ++k) {
        float t = SX[0][k] * SX[0][k];
#pragma unroll
        for (int d = 1; d < 12; ++d) t = fmaf(SX[d][k], SX[d][k], t);
        SX2[k] = t;
    }
    // ---- inclusive prefix sums: intra-lane serial + dpp add-scan ----
#pragma unroll
    for (int d = 0; d < 12; ++d) {
        float run = 0.f;
#pragma unroll
        for (int k = 0; k < 16; ++k) { run += SX[d][k]; SX[d][k] = run; }
        float ex = scan_add64(run) - run;   // exclusive lane offset
#pragma unroll
        for (int k = 0; k < 16; ++k) SX[d][k] += ex;
    }
    {
        float run = 0.f;
#pragma unroll
        for (int k = 0; k < 16; ++k) { run += SX2[k]; SX2[k] = run; }
        float ex = scan_add64(run) - run;
#pragma unroll
        for (int k = 0; k < 16; ++k) SX2[k] += ex;
    }
    float jp1[16];
#pragma unroll
    for (int k = 0; k < 16; ++k) jp1[k] = (float)(16 * lane + k + 1);

    float SA[16], SB[16], Dp[16];

// ---- S-compute chunks (next row), placed between chain stages ----
#define SN_CHUNK0(SN, inx) do { \
    float p2u = rdlane(p2r, (inx)); \
    _Pragma("unroll") for (int k = 0; k < 16; ++k) \
        SN[k] = fmaf(p2u, jp1[k], SX2[k]); \
    _Pragma("unroll") for (int d = 0; d < 3; ++d) { \
        float pv = rdlane(prm[d], (inx)); \
        _Pragma("unroll") for (int k = 0; k < 16; ++k) \
            SN[k] = fmaf(pv, SX[d][k], SN[k]); \
    } \
} while (0)

#define SN_CHUNKD(SN, inx, d0, d1) do { \
    _Pragma("unroll") for (int d = (d0); d < (d1); ++d) { \
        float pv = rdlane(prm[d], (inx)); \
        _Pragma("unroll") for (int k = 0; k < 16; ++k) \
            SN[k] = fmaf(pv, SX[d][k], SN[k]); \
    } \
} while (0)

#define COMPUTE_S_FULL(SN, inx) do { \
    SN_CHUNK0(SN, (inx)); SN_CHUNKD(SN, (inx), 3, 12); \
} while (0)

#define STORE_ROW(i) do { \
    if (lane >= 62) { \
        float* ob = out + blk * (32 * LOUT) + (lane - 62) * 16; \
        _Pragma("unroll") for (int c = 0; c < 4; ++c) { \
            v4f v = {Dp[4*c], Dp[4*c+1], Dp[4*c+2], Dp[4*c+3]}; \
            *(v4f*)(ob + (i) * 32 + 4 * c) = v; \
        } \
    } \
} while (0)

// One DP row, chain-minimized; optionally computes next row's S into SN.
#define ROW_CHAIN(i, SC, SN, CN) do { \
    float dsh = wshr1z(Dp[15]); dsh = l0 ? BIGF : dsh; \
    float se  = wshr1z(SC[15]); \
    float z[16]; \
    z[0] = fminf(dsh, Dp[0]) - se; \
    _Pragma("unroll") for (int k = 1; k < 16; ++k) \
        z[k] = fminf(Dp[k-1], Dp[k]) - SC[k-1]; \
    if (CN) { SN_CHUNK0(SN, (i) + 1); } \
    _Pragma("unroll") for (int g = 0; g < 4; ++g) { \
        _Pragma("unroll") for (int j = 1; j < 4; ++j) \
            z[4*g + j] = fminf(z[4*g + j - 1], z[4*g + j]); \
    } \
    if (CN) { SN_CHUNKD(SN, (i) + 1, 3, 6); } \
    float e1 = z[3]; \
    float e2 = fminf(e1, z[7]); \
    float e3 = fminf(e2, z[11]); \
    float m15 = fminf(e3, z[15]); \
    float t = scan_min64(m15); \
    if (CN) { SN_CHUNKD(SN, (i) + 1, 6, 9); } \
    float te = wshr1z(t); te = l0 ? BIGF : te; \
    float te1 = fminf(te, e1), te2 = fminf(te, e2), te3 = fminf(te, e3); \
    _Pragma("unroll") for (int k = 0;  k < 4;  ++k) Dp[k] = SC[k] + fminf(te,  z[k]); \
    _Pragma("unroll") for (int k = 4;  k < 8;  ++k) Dp[k] = SC[k] + fminf(te1, z[k]); \
    _Pragma("unroll") for (int k = 8;  k < 12; ++k) Dp[k] = SC[k] + fminf(te2, z[k]); \
    _Pragma("unroll") for (int k = 12; k < 16; ++k) Dp[k] = SC[k] + fminf(te3, z[k]); \
    if (CN) { SN_CHUNKD(SN, (i) + 1, 9, 12); } \
    STORE_ROW(i); \
} while (0)

    // ---- row 0: D = S(row 0) ----
    COMPUTE_S_FULL(SA, 0);
#pragma unroll
    for (int k = 0; k < 16; ++k) Dp[k] = SA[k];
    STORE_ROW(0);
    COMPUTE_S_FULL(SB, 1);   // prime the pipeline: S(row 1)

    // ---- rows 1..30: 2 rows/iter, S ping-pong SA<->SB (static indexing) ----
#pragma unroll 1
    for (int kk = 0; kk < 15; ++kk) {
        const int i0 = 2 * kk + 1;
        ROW_CHAIN(i0,     SB, SA, true);   // uses S(i0),   computes S(i0+1)
        ROW_CHAIN(i0 + 1, SA, SB, true);   // uses S(i0+1), computes S(i0+2)
    }
    // ---- row 31: no next row ----
    ROW_CHAIN(31, SB, SA, false);

#undef SN_CHUNK0
#undef SN_CHUNKD
#undef COMPUTE_S_FULL
#undef STORE_ROW
#undef ROW_CHAIN
}

extern "C" void kernel_launch(void* const* d_in, const int* in_sizes, int n_in,
                              void* d_out, int out_size, void* d_ws, size_t ws_size,
                              hipStream_t stream) {
    const float* x     = (const float*)d_in[0];   // [32,12,1024] f32
    const float* patts = (const float*)d_in[1];   // [32,12,32]   f32
    float* out         = (float*)d_out;           // [32,32,32,32] f32
    // CALIBRATION: 3 identical, serialized, idempotent launches.
    // dur_us ~= floor + 3K; baseline (1 launch) was 78.6 => K = (dur-78.6)/2.
    dtw_kernel<<<dim3(1024), dim3(64), 0, stream>>>(x, patts, out);
    dtw_kernel<<<dim3(1024), dim3(64), 0, stream>>>(x, patts, out);
    dtw_kernel<<<dim3(1024), dim3(64), 0, stream>>>(x, patts, out);
}

// Round 7
// 83.697 us; speedup vs baseline: 1.4978x; 1.4978x over previous
//
#include <hip/hip_runtime.h>

// DTW via min-plus scan for MI355X (gfx950). Round 21 (= r20 resubmitted;
// prior bench died on container acquisition -- same infra signature as r16,
// which passed unchanged on resubmit).
// B=32, N=32, D=12, P=32, L=1024, L_OUT=32, RHO=1 => w=1.
// r19 calibration: K = (125.36-78.64)/2 = 23.4us, harness floor ~55us.
// Row budget ~1600cy vs ~650cy issue; the ~950cy/row residual was invariant
// across issue -30%/-13% and chain -33% variants => not issue, not the fmin
// chain. Surviving explanation: ~300 live values > 256 VALU-addressable
// VGPRs => AGPR/scratch traffic on every row's 208-fma SX sweep.
// r20/r21: SX prefix arrays stored as packed fp16 pairs (192->96 VGPRs),
// consumed via v_fma_mix_f32 (same instr count, f16 operand via op_sel).
// SX2 + DP chain stay exact fp32; |dS| <~ 0.5 abs on outputs of hundreds.
// Steady-state demand ~210 <= 256 => no spill tax.
// Predict: dur 66-69 if spill model right; flat 78-79 if wrong.

#define BIGF 1e30f
#define LL   1024
#define LOUT 32

using v4f = __attribute__((ext_vector_type(4))) float;

template<int CTRL>
__device__ __forceinline__ float dpp_self(float v) {   // invalid lanes keep own
    return __int_as_float(__builtin_amdgcn_update_dpp(
        __float_as_int(v), __float_as_int(v), CTRL, 0xF, 0xF, false));
}
template<int CTRL>
__device__ __forceinline__ float dpp_zero(float v) {   // invalid lanes get 0
    return __int_as_float(__builtin_amdgcn_update_dpp(
        0, __float_as_int(v), CTRL, 0xF, 0xF, false));
}
template<int CTRL, int RM>
__device__ __forceinline__ float dpp_self_rm(float v) { // masked rows keep own
    return __int_as_float(__builtin_amdgcn_update_dpp(
        __float_as_int(v), __float_as_int(v), CTRL, RM, 0xF, false));
}
template<int CTRL, int RM>
__device__ __forceinline__ float dpp_zero_rm(float v) { // masked rows get 0
    return __int_as_float(__builtin_amdgcn_update_dpp(
        0, __float_as_int(v), CTRL, RM, 0xF, false));
}
// validated r2-r19: whole-wave shift right 1 lane; lane 0 <- 0
__device__ __forceinline__ float wshr1z(float v) {
    return __int_as_float(__builtin_amdgcn_update_dpp(
        0, __float_as_int(v), 0x138 /*wave_shr:1*/, 0xF, 0xF, false));
}
__device__ __forceinline__ float rdlane(float v, int l) {
    return __int_as_float(__builtin_amdgcn_readlane(__float_as_int(v), l));
}

// mixed-precision fma: d = a * f16(h2.half) + c   (VOP3P v_fma_mix_f32)
__device__ __forceinline__ float fmamix_lo(float a, int h2, float c) {
    float d;
    asm("v_fma_mix_f32 %0, %1, %2, %3 op_sel:[0,0,0] op_sel_hi:[0,1,0]"
        : "=v"(d) : "v"(a), "v"(h2), "v"(c));
    return d;
}
__device__ __forceinline__ float fmamix_hi(float a, int h2, float c) {
    float d;
    asm("v_fma_mix_f32 %0, %1, %2, %3 op_sel:[0,1,0] op_sel_hi:[0,1,0]"
        : "=v"(d) : "v"(a), "v"(h2), "v"(c));
    return d;
}
__device__ __forceinline__ int pack2h(float lo, float hi) {  // RN both halves
    unsigned short a = __builtin_bit_cast(unsigned short, (_Float16)lo);
    unsigned short b = __builtin_bit_cast(unsigned short, (_Float16)hi);
    return (int)((unsigned)a | ((unsigned)b << 16));
}

// inclusive wave64 min-scan, 6-op GCN form (validated r17-r19)
__device__ __forceinline__ float scan_min64(float t) {
    t = fminf(t, dpp_self<0x111>(t));            // row_shr:1
    t = fminf(t, dpp_self<0x112>(t));            // row_shr:2
    t = fminf(t, dpp_self<0x114>(t));            // row_shr:4
    t = fminf(t, dpp_self<0x118>(t));            // row_shr:8
    t = fminf(t, dpp_self_rm<0x142, 0xA>(t));    // row_bcast:15, rows 1,3
    t = fminf(t, dpp_self_rm<0x143, 0xC>(t));    // row_bcast:31, rows 2,3
    return t;
}
// inclusive wave64 add-scan (validated r17-r19)
__device__ __forceinline__ float scan_add64(float t) {
    t += dpp_zero<0x111>(t);
    t += dpp_zero<0x112>(t);
    t += dpp_zero<0x114>(t);
    t += dpp_zero<0x118>(t);
    t += dpp_zero_rm<0x142, 0xA>(t);
    t += dpp_zero_rm<0x143, 0xC>(t);
    return t;
}

__global__ __launch_bounds__(64)
__attribute__((amdgpu_waves_per_eu(1, 1)))
void dtw_kernel(const float* __restrict__ x, const float* __restrict__ patts,
                float* __restrict__ out) {
    const int lane = threadIdx.x;          // lane owns cols [16*lane, 16*lane+16)
    const bool l0  = (lane == 0);
    const int blk  = blockIdx.x;           // 0..1023 = (b,n)
    const int b    = blk >> 5, n = blk & 31;
    const float* __restrict__ xb = x + b * (12 * LL);
    const float* __restrict__ pn = patts + n * (12 * 32);

    // ---- pattern params into registers: lane r (r&31) holds row r ----
    float prm[12], p2r;
    {
        const int r = lane & 31;
        float s2 = 0.f;
#pragma unroll
        for (int d = 0; d < 12; ++d) {
            float v = pn[d * 32 + r];
            s2 = fmaf(v, v, s2);
            prm[d] = -2.0f * v;
        }
        p2r = s2;
    }

    // ---- streamed setup: per-dim load -> x^2 accum -> prefix -> fp16 pack ----
    // Peak pressure ~150 regs (SXh grows to 96; one fp32 dim in flight).
    int   SXh[12][8];    // packed fp16 pairs: cols (2p | 2p+1) of prefix sums
    float SX2[16];
#pragma unroll
    for (int k = 0; k < 16; ++k) SX2[k] = 0.f;

    v4f L[2][4];
#pragma unroll
    for (int c = 0; c < 4; ++c)
        L[0][c] = *(const v4f*)(xb + 16 * lane + 4 * c);
#pragma unroll
    for (int d = 0; d < 12; ++d) {
        if (d + 1 < 12) {
#pragma unroll
            for (int c = 0; c < 4; ++c)
                L[(d + 1) & 1][c] = *(const v4f*)(xb + (d + 1) * LL + 16 * lane + 4 * c);
        }
        float cur[16];
#pragma unroll
        for (int c = 0; c < 4; ++c) {
            cur[4*c+0] = L[d & 1][c].x; cur[4*c+1] = L[d & 1][c].y;
            cur[4*c+2] = L[d & 1][c].z; cur[4*c+3] = L[d & 1][c].w;
        }
#pragma unroll
        for (int k = 0; k < 16; ++k) SX2[k] = fmaf(cur[k], cur[k], SX2[k]);
        float run = 0.f;
#pragma unroll
        for (int k = 0; k < 16; ++k) { run += cur[k]; cur[k] = run; }
        float ex = scan_add64(run) - run;   // exclusive lane offset
#pragma unroll
        for (int k = 0; k < 16; ++k) cur[k] += ex;
#pragma unroll
        for (int p = 0; p < 8; ++p) SXh[d][p] = pack2h(cur[2*p], cur[2*p+1]);
    }
    {   // x^2 prefix stays exact fp32
        float run = 0.f;
#pragma unroll
        for (int k = 0; k < 16; ++k) { run += SX2[k]; SX2[k] = run; }
        float ex = scan_add64(run) - run;
#pragma unroll
        for (int k = 0; k < 16; ++k) SX2[k] += ex;
    }
    float jp1[16];
#pragma unroll
    for (int k = 0; k < 16; ++k) jp1[k] = (float)(16 * lane + k + 1);

    float SA[16], SB[16], Dp[16];

// ---- S-compute chunks: fp32 init + fp16-mix cross terms ----
#define SN_MIXD(SN, inx, d0, d1) do { \
    _Pragma("unroll") for (int d = (d0); d < (d1); ++d) { \
        float pv = rdlane(prm[d], (inx)); \
        _Pragma("unroll") for (int p = 0; p < 8; ++p) { \
            SN[2*p]   = fmamix_lo(pv, SXh[d][p], SN[2*p]); \
            SN[2*p+1] = fmamix_hi(pv, SXh[d][p], SN[2*p+1]); \
        } \
    } \
} while (0)

#define SN_CHUNK0(SN, inx) do { \
    float p2u = rdlane(p2r, (inx)); \
    _Pragma("unroll") for (int k = 0; k < 16; ++k) \
        SN[k] = fmaf(p2u, jp1[k], SX2[k]); \
    SN_MIXD(SN, (inx), 0, 3); \
} while (0)

#define COMPUTE_S_FULL(SN, inx) do { \
    SN_CHUNK0(SN, (inx)); SN_MIXD(SN, (inx), 3, 12); \
} while (0)

#define STORE_ROW(i) do { \
    if (lane >= 62) { \
        float* ob = out + blk * (32 * LOUT) + (lane - 62) * 16; \
        _Pragma("unroll") for (int c = 0; c < 4; ++c) { \
            v4f v = {Dp[4*c], Dp[4*c+1], Dp[4*c+2], Dp[4*c+3]}; \
            *(v4f*)(ob + (i) * 32 + 4 * c) = v; \
        } \
    } \
} while (0)

// One DP row (r18 chain, proven): z off-chain, groups-of-4 min, e-prefix,
// wave min-scan, te folds; next row's S interleaved between stages.
#define ROW_CHAIN(i, SC, SN, CN) do { \
    float dsh = wshr1z(Dp[15]); dsh = l0 ? BIGF : dsh; \
    float se  = wshr1z(SC[15]); \
    float z[16]; \
    z[0] = fminf(dsh, Dp[0]) - se; \
    _Pragma("unroll") for (int k = 1; k < 16; ++k) \
        z[k] = fminf(Dp[k-1], Dp[k]) - SC[k-1]; \
    if (CN) { SN_CHUNK0(SN, (i) + 1); } \
    _Pragma("unroll") for (int g = 0; g < 4; ++g) { \
        _Pragma("unroll") for (int j = 1; j < 4; ++j) \
            z[4*g + j] = fminf(z[4*g + j - 1], z[4*g + j]); \
    } \
    if (CN) { SN_MIXD(SN, (i) + 1, 3, 6); } \
    float e1 = z[3]; \
    float e2 = fminf(e1, z[7]); \
    float e3 = fminf(e2, z[11]); \
    float m15 = fminf(e3, z[15]); \
    float t = scan_min64(m15); \
    if (CN) { SN_MIXD(SN, (i) + 1, 6, 9); } \
    float te = wshr1z(t); te = l0 ? BIGF : te; \
    float te1 = fminf(te, e1), te2 = fminf(te, e2), te3 = fminf(te, e3); \
    _Pragma("unroll") for (int k = 0;  k < 4;  ++k) Dp[k] = SC[k] + fminf(te,  z[k]); \
    _Pragma("unroll") for (int k = 4;  k < 8;  ++k) Dp[k] = SC[k] + fminf(te1, z[k]); \
    _Pragma("unroll") for (int k = 8;  k < 12; ++k) Dp[k] = SC[k] + fminf(te2, z[k]); \
    _Pragma("unroll") for (int k = 12; k < 16; ++k) Dp[k] = SC[k] + fminf(te3, z[k]); \
    if (CN) { SN_MIXD(SN, (i) + 1, 9, 12); } \
    STORE_ROW(i); \
} while (0)

    // ---- row 0: D = S(row 0) ----
    COMPUTE_S_FULL(SA, 0);
#pragma unroll
    for (int k = 0; k < 16; ++k) Dp[k] = SA[k];
    STORE_ROW(0);
    COMPUTE_S_FULL(SB, 1);   // prime the pipeline: S(row 1)

    // ---- rows 1..30: 2 rows/iter, S ping-pong SA<->SB (static indexing) ----
#pragma unroll 1
    for (int kk = 0; kk < 15; ++kk) {
        const int i0 = 2 * kk + 1;
        ROW_CHAIN(i0,     SB, SA, true);   // uses S(i0),   computes S(i0+1)
        ROW_CHAIN(i0 + 1, SA, SB, true);   // uses S(i0+1), computes S(i0+2)
    }
    // ---- row 31: no next row ----
    ROW_CHAIN(31, SB, SA, false);

#undef SN_MIXD
#undef SN_CHUNK0
#undef COMPUTE_S_FULL
#undef STORE_ROW
#undef ROW_CHAIN
}

extern "C" void kernel_launch(void* const* d_in, const int* in_sizes, int n_in,
                              void* d_out, int out_size, void* d_ws, size_t ws_size,
                              hipStream_t stream) {
    const float* x     = (const float*)d_in[0];   // [32,12,1024] f32
    const float* patts = (const float*)d_in[1];   // [32,12,32]   f32
    float* out         = (float*)d_out;           // [32,32,32,32] f32
    dtw_kernel<<<dim3(1024), dim3(64), 0, stream>>>(x, patts, out);
}

// Round 9
// 82.650 us; speedup vs baseline: 1.5167x; 1.0127x over previous
//
#include <hip/hip_runtime.h>

// DTW via min-plus scan for MI355X (gfx950). Round 23 (= r22 with the
// compile-breaking leftover placeholder removed; design unchanged).
// B=32, N=32, D=12, P=32, L=1024, L_OUT=32, RHO=1 => w=1.
// r21 counters: VGPR=132 (no spills), VALUBusy=35%, Occupancy 10%
// (1 wave/SIMD), WRITE=output exactly; v_fma_mix_f32 is half-rate (+5.3us)
// -> reverted. Diagnosis: latency-bound; 2/3 of cycles are dead stalls.
// r23: two INDEPENDENT-timeline waves per problem (cols 0-511 / 512-1023),
// no lockstep barriers: wave0 runs free, publishes per-row boundary
// {Z=incl-min of z over cols 0-511, S_i[511], D_i[511]} to LDS with a
// marker flag (data -> lgkmcnt(0) -> flag); wave1 spin-checks (bounded,
// s_sleep) and folds Z into its te. 2048 waves / 1024 SIMDs = 2/SIMD.
// Predict: VALUBusy 35->55-75%, dur 83.7 -> 67-72. Flat => shared-pipe
// stalls, structural floor.

#define BIGF 1e30f
#define LL   1024
#define LOUT 32

using v4f = __attribute__((ext_vector_type(4))) float;

template<int CTRL>
__device__ __forceinline__ float dpp_self(float v) {   // invalid lanes keep own
    return __int_as_float(__builtin_amdgcn_update_dpp(
        __float_as_int(v), __float_as_int(v), CTRL, 0xF, 0xF, false));
}
template<int CTRL>
__device__ __forceinline__ float dpp_zero(float v) {   // invalid lanes get 0
    return __int_as_float(__builtin_amdgcn_update_dpp(
        0, __float_as_int(v), CTRL, 0xF, 0xF, false));
}
template<int CTRL, int RM>
__device__ __forceinline__ float dpp_self_rm(float v) { // masked rows keep own
    return __int_as_float(__builtin_amdgcn_update_dpp(
        __float_as_int(v), __float_as_int(v), CTRL, RM, 0xF, false));
}
template<int CTRL, int RM>
__device__ __forceinline__ float dpp_zero_rm(float v) { // masked rows get 0
    return __int_as_float(__builtin_amdgcn_update_dpp(
        0, __float_as_int(v), CTRL, RM, 0xF, false));
}
// validated r2-r21: whole-wave shift right 1 lane; lane 0 <- 0
__device__ __forceinline__ float wshr1z(float v) {
    return __int_as_float(__builtin_amdgcn_update_dpp(
        0, __float_as_int(v), 0x138 /*wave_shr:1*/, 0xF, 0xF, false));
}
__device__ __forceinline__ float rdlane(float v, int l) {
    return __int_as_float(__builtin_amdgcn_readlane(__float_as_int(v), l));
}

// inclusive wave64 min-scan, 6-op GCN form (validated r17-r21)
__device__ __forceinline__ float scan_min64(float t) {
    t = fminf(t, dpp_self<0x111>(t));            // row_shr:1
    t = fminf(t, dpp_self<0x112>(t));            // row_shr:2
    t = fminf(t, dpp_self<0x114>(t));            // row_shr:4
    t = fminf(t, dpp_self<0x118>(t));            // row_shr:8
    t = fminf(t, dpp_self_rm<0x142, 0xA>(t));    // row_bcast:15, rows 1,3
    t = fminf(t, dpp_self_rm<0x143, 0xC>(t));    // row_bcast:31, rows 2,3
    return t;
}
// inclusive wave64 add-scan (validated r17-r21)
__device__ __forceinline__ float scan_add64(float t) {
    t += dpp_zero<0x111>(t);
    t += dpp_zero<0x112>(t);
    t += dpp_zero<0x114>(t);
    t += dpp_zero<0x118>(t);
    t += dpp_zero_rm<0x142, 0xA>(t);
    t += dpp_zero_rm<0x143, 0xC>(t);
    return t;
}

__global__ __launch_bounds__(128, 2)   // 2 waves/EU target: VGPR cap 256
void dtw_kernel(const float* __restrict__ x, const float* __restrict__ patts,
                float* __restrict__ out) {
    const int tid  = threadIdx.x;
    const int lane = tid & 63;
    const int wv   = tid >> 6;          // wave0: cols 0..511, wave1: 512..1023
    const bool l0  = (lane == 0);
    const int blk  = blockIdx.x;        // 0..1023 = (b,n)
    const int b    = blk >> 5, n = blk & 31;
    const float* __restrict__ xb = x + b * (12 * LL);
    const float* __restrict__ pn = patts + n * (12 * 32);

    __shared__ float ldsT[13];          // setup prefix totals (12 dims + x^2)
    __shared__ float pkgf[32][4];       // per row: {Z, S_i[511], D_i[511], marker}

    if (tid < 32) pkgf[tid][3] = 0.0f;  // clear markers before the one barrier

    // ---- pattern params: lane r (r&31) holds row r ----
    float prm[12], p2r;
    {
        const int r = lane & 31;
        float s2 = 0.f;
#pragma unroll
        for (int d = 0; d < 12; ++d) {
            float v = pn[d * 32 + r];
            s2 = fmaf(v, v, s2);
            prm[d] = -2.0f * v;
        }
        p2r = s2;
    }

    // ---- x half-slice (8 cols/lane), prefix sums; wave0 publishes totals ----
    const int colbase = (wv << 9) + (lane << 3);
    float SX[12][8];
#pragma unroll
    for (int d = 0; d < 12; ++d) {
        v4f a = *(const v4f*)(xb + d * LL + colbase);
        v4f c = *(const v4f*)(xb + d * LL + colbase + 4);
        SX[d][0] = a.x; SX[d][1] = a.y; SX[d][2] = a.z; SX[d][3] = a.w;
        SX[d][4] = c.x; SX[d][5] = c.y; SX[d][6] = c.z; SX[d][7] = c.w;
    }
    float SX2[8];
#pragma unroll
    for (int k = 0; k < 8; ++k) {
        float t = SX[0][k] * SX[0][k];
#pragma unroll
        for (int d = 1; d < 12; ++d) t = fmaf(SX[d][k], SX[d][k], t);
        SX2[k] = t;
    }
#pragma unroll
    for (int d = 0; d < 12; ++d) {
        float run = 0.f;
#pragma unroll
        for (int k = 0; k < 8; ++k) { run += SX[d][k]; SX[d][k] = run; }
        float inc = scan_add64(run);
        if (wv == 0 && lane == 63) ldsT[d] = inc;
        float ex = inc - run;
#pragma unroll
        for (int k = 0; k < 8; ++k) SX[d][k] += ex;
    }
    {
        float run = 0.f;
#pragma unroll
        for (int k = 0; k < 8; ++k) { run += SX2[k]; SX2[k] = run; }
        float inc = scan_add64(run);
        if (wv == 0 && lane == 63) ldsT[12] = inc;
        float ex = inc - run;
#pragma unroll
        for (int k = 0; k < 8; ++k) SX2[k] += ex;
    }
    __syncthreads();                    // the ONLY barrier
    if (wv == 1) {
#pragma unroll
        for (int d = 0; d < 12; ++d) {
            float off = ldsT[d];
#pragma unroll
            for (int k = 0; k < 8; ++k) SX[d][k] += off;
        }
        float off2 = ldsT[12];
#pragma unroll
        for (int k = 0; k < 8; ++k) SX2[k] += off2;
    }
    float jp1[8];
#pragma unroll
    for (int k = 0; k < 8; ++k) jp1[k] = (float)(colbase + k + 1);

    float S[8], Dp[8];

#define COMPUTE_S(i) do { \
    float p2u = rdlane(p2r, (i)); \
    _Pragma("unroll") for (int k = 0; k < 8; ++k) \
        S[k] = fmaf(p2u, jp1[k], SX2[k]); \
    _Pragma("unroll") for (int d = 0; d < 12; ++d) { \
        float pv = rdlane(prm[d], (i)); \
        _Pragma("unroll") for (int k = 0; k < 8; ++k) \
            S[k] = fmaf(pv, SX[d][k], S[k]); \
    } \
} while (0)

#define PUBLISH(i, Zv) do { \
    if (lane == 63) { \
        pkgf[i][0] = (Zv); pkgf[i][1] = S[7]; pkgf[i][2] = Dp[7]; \
        asm volatile("s_waitcnt lgkmcnt(0)" ::: "memory"); \
        *(volatile int*)&pkgf[i][3] = (i) + 1; \
    } \
} while (0)

#define STORE_ROW(i) do { \
    if (lane >= 60) { \
        float* ob = out + blk * (32 * LOUT) + (i) * LOUT + (lane - 60) * 8; \
        v4f va = {Dp[0], Dp[1], Dp[2], Dp[3]}; \
        v4f vb = {Dp[4], Dp[5], Dp[6], Dp[7]}; \
        *(v4f*)ob = va; *(v4f*)(ob + 4) = vb; \
    } \
} while (0)

    if (wv == 0) {
        // ---- producer: runs free, never waits ----
        COMPUTE_S(0);
#pragma unroll
        for (int k = 0; k < 8; ++k) Dp[k] = S[k];
        PUBLISH(0, BIGF);
#pragma unroll 1
        for (int i = 1; i < 32; ++i) {
            COMPUTE_S(i);
            float dsh = wshr1z(Dp[7]); dsh = l0 ? BIGF : dsh;
            float se  = wshr1z(S[7]);               // lane0 -> 0 = S[-1]
            float m[8];
            m[0] = fminf(dsh, Dp[0]) - se;
#pragma unroll
            for (int k = 1; k < 8; ++k)
                m[k] = fminf(m[k-1], fminf(Dp[k-1], Dp[k]) - S[k-1]);
            float t  = scan_min64(m[7]);
            float te = wshr1z(t); te = l0 ? BIGF : te;
#pragma unroll
            for (int k = 0; k < 8; ++k) Dp[k] = S[k] + fminf(te, m[k]);
            PUBLISH(i, t);
        }
    } else {
        // ---- consumer: owns all 32 output cols (992..1023) ----
        COMPUTE_S(0);
#pragma unroll
        for (int k = 0; k < 8; ++k) Dp[k] = S[k];
        STORE_ROW(0);
        float Db;
        {
            volatile int* fl = (volatile int*)&pkgf[0][3];
            int cnt = 0;
            while (*fl != 1) { if (++cnt > 1000000) break; __builtin_amdgcn_s_sleep(2); }
            asm volatile("" ::: "memory");
            Db = pkgf[0][2];                        // D_0[511]
        }
#pragma unroll 1
        for (int i = 1; i < 32; ++i) {
            COMPUTE_S(i);                           // independent of package
            volatile int* fl = (volatile int*)&pkgf[i][3];
            int cnt = 0;
            while (*fl != i + 1) { if (++cnt > 1000000) break; __builtin_amdgcn_s_sleep(2); }
            asm volatile("" ::: "memory");
            float Z  = pkgf[i][0];                  // incl min over cols 0..511
            float Sb = pkgf[i][1];                  // S_i[511]
            float dsh = wshr1z(Dp[7]); dsh = l0 ? Db : dsh;   // D_{i-1}[511]
            float se  = wshr1z(S[7]);  se  = l0 ? Sb : se;
            float m[8];
            m[0] = fminf(dsh, Dp[0]) - se;
#pragma unroll
            for (int k = 1; k < 8; ++k)
                m[k] = fminf(m[k-1], fminf(Dp[k-1], Dp[k]) - S[k-1]);
            float t  = scan_min64(m[7]);
            float te = wshr1z(t); te = l0 ? BIGF : te;
            te = fminf(te, Z);
#pragma unroll
            for (int k = 0; k < 8; ++k) Dp[k] = S[k] + fminf(te, m[k]);
            Db = pkgf[i][2];                        // D_i[511] for next row
            STORE_ROW(i);
        }
    }

#undef COMPUTE_S
#undef PUBLISH
#undef STORE_ROW
}

extern "C" void kernel_launch(void* const* d_in, const int* in_sizes, int n_in,
                              void* d_out, int out_size, void* d_ws, size_t ws_size,
                              hipStream_t stream) {
    const float* x     = (const float*)d_in[0];   // [32,12,1024] f32
    const float* patts = (const float*)d_in[1];   // [32,12,32]   f32
    float* out         = (float*)d_out;           // [32,32,32,32] f32
    dtw_kernel<<<dim3(1024), dim3(128), 0, stream>>>(x, patts, out);
}

// Round 10
// 79.536 us; speedup vs baseline: 1.5761x; 1.0392x over previous
//
#include <hip/hip_runtime.h>

// DTW via min-plus scan for MI355X (gfx950). Round 24.
// B=32, N=32, D=12, P=32, L=1024, L_OUT=32, RHO=1 => w=1.
// Model (fit r14-r23): per-row wall 1570cy = ~450cy S-fma issue + ~1100cy
// NAKED chain (21 serial cross-lane/fmin ops x ~50cy DPP dep latency +
// hazards). Compiler clusters all independent fmas BEFORE the chain
// (r18's source interleave was re-scheduled away); r23 proved anything
// ADDED to the chain (LDS handoff) shows up 1:1 (+300cy/row).
// r24: r18 math bit-identical, but the row is cut into 11 regions with
// __builtin_amdgcn_sched_barrier(0) fences: [chain stage (2-4 serial
// ops)][S(i+1) chunk (32-48 fmas)] alternating, so in-order issue fills
// every chain-latency shadow by construction.
// Predict: K 23.4 -> 11-13us, dur 78.6 -> 66.5-69.5. Flat => cross-lane
// latency >> model, target the DPP ops next. Worse => revert r18.

#define BIGF 1e30f
#define LL   1024
#define LOUT 32

using v4f = __attribute__((ext_vector_type(4))) float;

#define SBAR() __builtin_amdgcn_sched_barrier(0)

template<int CTRL>
__device__ __forceinline__ float dpp_self(float v) {   // invalid lanes keep own
    return __int_as_float(__builtin_amdgcn_update_dpp(
        __float_as_int(v), __float_as_int(v), CTRL, 0xF, 0xF, false));
}
template<int CTRL>
__device__ __forceinline__ float dpp_zero(float v) {   // invalid lanes get 0
    return __int_as_float(__builtin_amdgcn_update_dpp(
        0, __float_as_int(v), CTRL, 0xF, 0xF, false));
}
template<int CTRL, int RM>
__device__ __forceinline__ float dpp_self_rm(float v) { // masked rows keep own
    return __int_as_float(__builtin_amdgcn_update_dpp(
        __float_as_int(v), __float_as_int(v), CTRL, RM, 0xF, false));
}
template<int CTRL, int RM>
__device__ __forceinline__ float dpp_zero_rm(float v) { // masked rows get 0
    return __int_as_float(__builtin_amdgcn_update_dpp(
        0, __float_as_int(v), CTRL, RM, 0xF, false));
}
// validated r2-r23: whole-wave shift right 1 lane; lane 0 <- 0
__device__ __forceinline__ float wshr1z(float v) {
    return __int_as_float(__builtin_amdgcn_update_dpp(
        0, __float_as_int(v), 0x138 /*wave_shr:1*/, 0xF, 0xF, false));
}
__device__ __forceinline__ float rdlane(float v, int l) {
    return __int_as_float(__builtin_amdgcn_readlane(__float_as_int(v), l));
}

// inclusive wave64 add-scan, 6-op GCN form (validated r17-r23; setup only)
__device__ __forceinline__ float scan_add64(float t) {
    t += dpp_zero<0x111>(t);
    t += dpp_zero<0x112>(t);
    t += dpp_zero<0x114>(t);
    t += dpp_zero<0x118>(t);
    t += dpp_zero_rm<0x142, 0xA>(t);
    t += dpp_zero_rm<0x143, 0xC>(t);
    return t;
}

__global__ __launch_bounds__(64)
__attribute__((amdgpu_waves_per_eu(1, 1)))   // 1 wave/EU: full register file
void dtw_kernel(const float* __restrict__ x, const float* __restrict__ patts,
                float* __restrict__ out) {
    const int lane = threadIdx.x;          // lane owns cols [16*lane, 16*lane+16)
    const bool l0  = (lane == 0);
    const int blk  = blockIdx.x;           // 0..1023 = (b,n)
    const int b    = blk >> 5, n = blk & 31;
    const float* __restrict__ xb = x + b * (12 * LL);
    const float* __restrict__ pn = patts + n * (12 * 32);

    // ---- pattern params into registers: lane r (r&31) holds row r ----
    float prm[12], p2r;
    {
        const int r = lane & 31;
        float s2 = 0.f;
#pragma unroll
        for (int d = 0; d < 12; ++d) {
            float v = pn[d * 32 + r];
            s2 = fmaf(v, v, s2);
            prm[d] = -2.0f * v;
        }
        p2r = s2;
    }

    // ---- x slice -> scalar regs (coalesced 16B/lane loads) ----
    float SX[12][16];
#pragma unroll
    for (int d = 0; d < 12; ++d) {
#pragma unroll
        for (int c = 0; c < 4; ++c) {
            v4f v = *(const v4f*)(xb + d * LL + 16 * lane + 4 * c);
            SX[d][4 * c + 0] = v.x;
            SX[d][4 * c + 1] = v.y;
            SX[d][4 * c + 2] = v.z;
            SX[d][4 * c + 3] = v.w;
        }
    }
    // x^2 from raw values
    float SX2[16];
#pragma unroll
    for (int k = 0; k < 16; ++k) {
        float t = SX[0][k] * SX[0][k];
#pragma unroll
        for (int d = 1; d < 12; ++d) t = fmaf(SX[d][k], SX[d][k], t);
        SX2[k] = t;
    }
    // ---- inclusive prefix sums: intra-lane serial + dpp add-scan ----
#pragma unroll
    for (int d = 0; d < 12; ++d) {
        float run = 0.f;
#pragma unroll
        for (int k = 0; k < 16; ++k) { run += SX[d][k]; SX[d][k] = run; }
        float ex = scan_add64(run) - run;   // exclusive lane offset
#pragma unroll
        for (int k = 0; k < 16; ++k) SX[d][k] += ex;
    }
    {
        float run = 0.f;
#pragma unroll
        for (int k = 0; k < 16; ++k) { run += SX2[k]; SX2[k] = run; }
        float ex = scan_add64(run) - run;
#pragma unroll
        for (int k = 0; k < 16; ++k) SX2[k] += ex;
    }
    float jp1[16];
#pragma unroll
    for (int k = 0; k < 16; ++k) jp1[k] = (float)(16 * lane + k + 1);

    float SA[16], SB[16], Dp[16];

// ---- S(i+1) chunks ----
#define SN_INIT2(SN, inx) do { \
    float p2u = rdlane(p2r, (inx)); \
    _Pragma("unroll") for (int k = 0; k < 16; ++k) \
        SN[k] = fmaf(p2u, jp1[k], SX2[k]); \
    _Pragma("unroll") for (int d = 0; d < 2; ++d) { \
        float pv = rdlane(prm[d], (inx)); \
        _Pragma("unroll") for (int k = 0; k < 16; ++k) \
            SN[k] = fmaf(pv, SX[d][k], SN[k]); \
    } \
} while (0)

#define SN_DIMS(SN, inx, d0, d1) do { \
    _Pragma("unroll") for (int d = (d0); d < (d1); ++d) { \
        float pv = rdlane(prm[d], (inx)); \
        _Pragma("unroll") for (int k = 0; k < 16; ++k) \
            SN[k] = fmaf(pv, SX[d][k], SN[k]); \
    } \
} while (0)

#define COMPUTE_S_FULL(SN, inx) do { \
    SN_INIT2(SN, (inx)); SN_DIMS(SN, (inx), 2, 12); \
} while (0)

#define STORE_ROW(i) do { \
    if (lane >= 62) { \
        float* ob = out + blk * (32 * LOUT) + (lane - 62) * 16; \
        _Pragma("unroll") for (int c = 0; c < 4; ++c) { \
            v4f v = {Dp[4*c], Dp[4*c+1], Dp[4*c+2], Dp[4*c+3]}; \
            *(v4f*)(ob + (i) * 32 + 4 * c) = v; \
        } \
    } \
} while (0)

// One DP row, r18 math bit-identical, fence-pipelined:
// chain stages and S(i+1) chunks alternate between sched_barrier(0)s so
// each chunk's issue covers the previous stage's cross-lane latency.
#define ROW_CHAIN(i, SC, SN, CN) do { \
    /* R1: boundary DPPs issue */ \
    float dshr = wshr1z(Dp[15]); \
    float se   = wshr1z(SC[15]); \
    SBAR(); \
    /* R2: chunk A (p2-init + dims 0-1) covers DPP latency */ \
    if (CN) { SN_INIT2(SN, (i) + 1); } \
    SBAR(); \
    /* R3: z[] + group-of-4 local mins */ \
    float z[16]; \
    z[0] = fminf(l0 ? BIGF : dshr, Dp[0]) - se; \
    _Pragma("unroll") for (int k = 1; k < 16; ++k) \
        z[k] = fminf(Dp[k-1], Dp[k]) - SC[k-1]; \
    _Pragma("unroll") for (int g = 0; g < 4; ++g) { \
        _Pragma("unroll") for (int j = 1; j < 4; ++j) \
            z[4*g + j] = fminf(z[4*g + j - 1], z[4*g + j]); \
    } \
    SBAR(); \
    /* R4: chunk B (dims 2-4) */ \
    if (CN) { SN_DIMS(SN, (i) + 1, 2, 5); } \
    SBAR(); \
    /* R5: e-prefix + scan DPP 1-2 */ \
    float e1 = z[3]; \
    float e2 = fminf(e1, z[7]); \
    float e3 = fminf(e2, z[11]); \
    float t  = fminf(e3, z[15]); \
    t = fminf(t, dpp_self<0x111>(t)); \
    t = fminf(t, dpp_self<0x112>(t)); \
    SBAR(); \
    /* R6: chunk C (dims 5-7) */ \
    if (CN) { SN_DIMS(SN, (i) + 1, 5, 8); } \
    SBAR(); \
    /* R7: scan DPP 3-4 */ \
    t = fminf(t, dpp_self<0x114>(t)); \
    t = fminf(t, dpp_self<0x118>(t)); \
    SBAR(); \
    /* R8: chunk D (dims 8-9) */ \
    if (CN) { SN_DIMS(SN, (i) + 1, 8, 10); } \
    SBAR(); \
    /* R9: scan DPP 5-6 + te */ \
    t = fminf(t, dpp_self_rm<0x142, 0xA>(t)); \
    t = fminf(t, dpp_self_rm<0x143, 0xC>(t)); \
    float te = wshr1z(t); \
    SBAR(); \
    /* R10: chunk E (dims 10-11) */ \
    if (CN) { SN_DIMS(SN, (i) + 1, 10, 12); } \
    SBAR(); \
    /* R11: te folds + Dp update + store */ \
    te = l0 ? BIGF : te; \
    float te1 = fminf(te, e1), te2 = fminf(te, e2), te3 = fminf(te, e3); \
    _Pragma("unroll") for (int k = 0;  k < 4;  ++k) Dp[k] = SC[k] + fminf(te,  z[k]); \
    _Pragma("unroll") for (int k = 4;  k < 8;  ++k) Dp[k] = SC[k] + fminf(te1, z[k]); \
    _Pragma("unroll") for (int k = 8;  k < 12; ++k) Dp[k] = SC[k] + fminf(te2, z[k]); \
    _Pragma("unroll") for (int k = 12; k < 16; ++k) Dp[k] = SC[k] + fminf(te3, z[k]); \
    STORE_ROW(i); \
    SBAR(); \
} while (0)

    // ---- row 0: D = S(row 0) ----
    COMPUTE_S_FULL(SA, 0);
#pragma unroll
    for (int k = 0; k < 16; ++k) Dp[k] = SA[k];
    STORE_ROW(0);
    COMPUTE_S_FULL(SB, 1);   // prime the pipeline: S(row 1)

    // ---- rows 1..30: 2 rows/iter, S ping-pong SA<->SB (static indexing) ----
#pragma unroll 1
    for (int kk = 0; kk < 15; ++kk) {
        const int i0 = 2 * kk + 1;
        ROW_CHAIN(i0,     SB, SA, true);   // uses S(i0),   computes S(i0+1)
        ROW_CHAIN(i0 + 1, SA, SB, true);   // uses S(i0+1), computes S(i0+2)
    }
    // ---- row 31: no next row ----
    ROW_CHAIN(31, SB, SA, false);

#undef SN_INIT2
#undef SN_DIMS
#undef COMPUTE_S_FULL
#undef STORE_ROW
#undef ROW_CHAIN
}

extern "C" void kernel_launch(void* const* d_in, const int* in_sizes, int n_in,
                              void* d_out, int out_size, void* d_ws, size_t ws_size,
                              hipStream_t stream) {
    const float* x     = (const float*)d_in[0];   // [32,12,1024] f32
    const float* patts = (const float*)d_in[1];   // [32,12,32]   f32
    float* out         = (float*)d_out;           // [32,32,32,32] f32
    dtw_kernel<<<dim3(1024), dim3(64), 0, stream>>>(x, patts, out);
}